// Round 4
// baseline (1173.044 us; speedup 1.0000x reference)
//
#include <hip/hip_runtime.h>
#include <hip/hip_bf16.h>

// GATv2 x3 layers, MI355X. f32 in/out; edge_index int32.
// R4: head-split score kernel (We slice in 16 VGPRs, no LDS), CSR-ordered
// edge processing with pre-permuted edge attrs, scores stored [head][pos]
// for coalesced softmax gathers, (node,head)-parallel aggregate, LDS-free xl.

#define NN 10000    // nodes
#define NE 200000   // edges
#define ND 128      // node dim (layer 0 input)
#define ED 16       // edge dim
#define CD 64       // conv dim (per head)
#define NH 5        // heads
#define HC 320      // NH*CD
#define EF 210000   // NE + NN (with self loops)
#define NEG 0.2f
#define GX 512      // k_score blocks per head
#define CH 103      // edges per wave in k_score: 512*4*103 >= EF

// ---- CSR build: count ----
__global__ void k_count(const int* __restrict__ dst, int* __restrict__ deg) {
  int e = blockIdx.x * blockDim.x + threadIdx.x;
  if (e >= NE) return;
  atomicAdd(&deg[dst[e]], 1);
}

// ---- CSR build: exclusive scan (single block) ----
__global__ __launch_bounds__(256) void k_scan(const int* __restrict__ deg,
                                              int* __restrict__ rowptr) {
  __shared__ int part[256];
  int t = threadIdx.x;
  int base = t * 40;
  int local[40];
  int s = 0;
  #pragma unroll
  for (int j = 0; j < 40; j++) {
    int i = base + j;
    local[j] = (i < NN) ? deg[i] : 0;
    s += local[j];
  }
  part[t] = s;
  __syncthreads();
  for (int off = 1; off < 256; off <<= 1) {
    int v = (t >= off) ? part[t - off] : 0;
    __syncthreads();
    part[t] += v;
    __syncthreads();
  }
  int prefix = (t > 0) ? part[t - 1] : 0;
  #pragma unroll
  for (int j = 0; j < 40; j++) {
    int i = base + j;
    if (i < NN) rowptr[i] = prefix;
    prefix += local[j];
  }
  if (t == 255) rowptr[NN] = prefix;
}

// ---- CSR build: fill ----
__global__ void k_fill(const int* __restrict__ ei, const int* __restrict__ rowptr,
                       int* __restrict__ cursor, int* __restrict__ csr_eid,
                       int* __restrict__ csr_src, int* __restrict__ csr_dst) {
  int e = blockIdx.x * blockDim.x + threadIdx.x;
  if (e >= NE) return;
  int d = ei[NE + e];
  int slot = atomicAdd(&cursor[d], 1);
  int pos = rowptr[d] + slot;
  csr_eid[pos] = e;
  csr_src[pos] = ei[e];
  csr_dst[pos] = d;
}

// ---- loop_attr = mean of incoming edge_attr (gather, wave per node) ----
__global__ __launch_bounds__(256) void k_loopattr(const int* __restrict__ csr_eid,
                                                  const int* __restrict__ rowptr,
                                                  const float* __restrict__ eattr,
                                                  float* __restrict__ loop_attr) {
  int wave = threadIdx.x >> 6, lane = threadIdx.x & 63;
  int d = blockIdx.x * 4 + wave;
  if (d >= NN) return;
  int g = lane >> 4, k = lane & 15;
  int b = rowptr[d], n = rowptr[d + 1] - b;
  float s = 0.f;
  for (int i = g; i < n; i += 4)
    s += eattr[(size_t)csr_eid[b + i] * ED + k];
  s += __shfl_xor(s, 16, 64);
  s += __shfl_xor(s, 32, 64);
  if (g == 0) loop_attr[d * ED + k] = s / fmaxf((float)n, 1.0f);
}

// ---- ea_csr[p] = edge attrs in CSR order; self-loop attrs appended ----
__global__ void k_eacsr(const int* __restrict__ csr_eid, const float* __restrict__ eattr,
                        const float* __restrict__ loop_attr, float* __restrict__ ea_csr) {
  int idx = blockIdx.x * blockDim.x + threadIdx.x;  // (p, quad)
  if (idx >= EF * 4) return;
  int p = idx >> 2, q = idx & 3;
  const float4* sp;
  if (p < NE) sp = (const float4*)(eattr + (size_t)csr_eid[p] * ED);
  else        sp = (const float4*)(loop_attr + (size_t)(p - NE) * ED);
  ((float4*)(ea_csr + (size_t)p * ED))[q] = sp[q];
}

// ---- xl = h @ Wl + bl  (no LDS; h rows via uniform broadcast loads) ----
template <int D>
__global__ __launch_bounds__(320) void k_xl(const float* __restrict__ h,
                                            const float* __restrict__ Wl,
                                            const float* __restrict__ bl,
                                            float* __restrict__ xl) {
  constexpr int NPB = 8;
  int node0 = blockIdx.x * NPB;
  int t = threadIdx.x;  // output column 0..319
  float acc[NPB];
  #pragma unroll
  for (int i = 0; i < NPB; i++) acc[i] = 0.f;
  for (int k = 0; k < D; k += 4) {
    float w0 = Wl[(k + 0) * HC + t];
    float w1 = Wl[(k + 1) * HC + t];
    float w2 = Wl[(k + 2) * HC + t];
    float w3 = Wl[(k + 3) * HC + t];
    #pragma unroll
    for (int i = 0; i < NPB; i++) {
      float4 hv = *(const float4*)(h + (size_t)(node0 + i) * D + k);
      acc[i] += hv.x * w0 + hv.y * w1 + hv.z * w2 + hv.w * w3;
    }
  }
  float bv = bl[t];
  #pragma unroll
  for (int i = 0; i < NPB; i++)
    xl[(size_t)(node0 + i) * HC + t] = acc[i] + bv;
}

// ---- scores: wave per (edge-chunk, head); We slice in registers ----
__global__ __launch_bounds__(256) void k_score(
    const int* __restrict__ csr_src, const int* __restrict__ csr_dst,
    const float* __restrict__ ea_csr, const float* __restrict__ xl,
    const float* __restrict__ We, const float* __restrict__ att,
    float* __restrict__ scoreP) {
  int h = blockIdx.y;
  int lane = threadIdx.x & 63, w = threadIdx.x >> 6;
  int wid = blockIdx.x * 4 + w;
  float Wr[ED];
  #pragma unroll
  for (int k = 0; k < ED; k++) Wr[k] = We[k * HC + h * CD + lane];
  float attv = att[h * CD + lane];
  float* sp = scoreP + (size_t)h * EF;
  int p0 = wid * CH, p1 = min(p0 + CH, EF);
  for (int p = p0; p < p1; p++) {
    int s, d;
    if (p < NE) { s = csr_src[p]; d = csr_dst[p]; }
    else        { s = d = p - NE; }
    const float4* eap = (const float4*)(ea_csr + (size_t)p * ED);
    float4 e0 = eap[0], e1 = eap[1], e2 = eap[2], e3 = eap[3];
    float v = xl[(size_t)s * HC + h * CD + lane] + xl[(size_t)d * HC + h * CD + lane];
    v += e0.x * Wr[0]  + e0.y * Wr[1]  + e0.z * Wr[2]  + e0.w * Wr[3];
    v += e1.x * Wr[4]  + e1.y * Wr[5]  + e1.z * Wr[6]  + e1.w * Wr[7];
    v += e2.x * Wr[8]  + e2.y * Wr[9]  + e2.z * Wr[10] + e2.w * Wr[11];
    v += e3.x * Wr[12] + e3.y * Wr[13] + e3.z * Wr[14] + e3.w * Wr[15];
    v = v > 0.f ? v : NEG * v;
    float t = v * attv;
    #pragma unroll
    for (int off = 1; off < 64; off <<= 1) t += __shfl_xor(t, off, 64);
    if (lane == 0) sp[p] = t;
  }
}

// ---- softmax + aggregate per (node, head); partial[d][h][c] out ----
__global__ __launch_bounds__(256) void k_gat(const int* __restrict__ csr_src,
                                             const int* __restrict__ rowptr,
                                             const float* __restrict__ scoreP,
                                             const float* __restrict__ xl,
                                             float* __restrict__ partial) {
  int w = threadIdx.x >> 6, lane = threadIdx.x & 63;
  int d = blockIdx.x * 4 + w;
  int h = blockIdx.y;
  if (d >= NN) return;
  int b = rowptr[d], n = rowptr[d + 1] - b;  // + self loop at pos NE+d
  const float* sp = scoreP + (size_t)h * EF;
  // max
  float m = -1e30f;
  for (int i = lane; i <= n; i += 64)
    m = fmaxf(m, sp[(i < n) ? b + i : NE + d]);
  #pragma unroll
  for (int off = 1; off < 64; off <<= 1) m = fmaxf(m, __shfl_xor(m, off, 64));
  // denom
  float dn = 0.f;
  for (int i = lane; i <= n; i += 64)
    dn += __expf(sp[(i < n) ? b + i : NE + d] - m);
  #pragma unroll
  for (int off = 1; off < 64; off <<= 1) dn += __shfl_xor(dn, off, 64);
  float rdn = 1.0f / dn;
  // accumulate (serial over edges; lane = channel)
  float acc = 0.f;
  for (int i = 0; i <= n; i++) {
    int pos = (i < n) ? b + i : NE + d;
    int s   = (i < n) ? csr_src[pos] : d;
    float alpha = __expf(sp[pos] - m) * rdn;
    acc += alpha * xl[(size_t)s * HC + h * CD + lane];
  }
  partial[((size_t)d * NH + h) * CD + lane] = acc;
}

// ---- combine heads + bias + elu ----
__global__ void k_comb(const float* __restrict__ partial, const float* __restrict__ bias,
                       float* __restrict__ out) {
  int i = blockIdx.x * blockDim.x + threadIdx.x;
  if (i >= NN * CD) return;
  int d = i >> 6, c = i & 63;
  float v = 0.f;
  #pragma unroll
  for (int h = 0; h < NH; h++) v += partial[((size_t)d * NH + h) * CD + c];
  v = v * (1.0f / NH) + bias[c];
  v = v > 0.f ? v : expm1f(v);
  out[i] = v;
}

extern "C" void kernel_launch(void* const* d_in, const int* in_sizes, int n_in,
                              void* d_out, int out_size, void* d_ws, size_t ws_size,
                              hipStream_t stream) {
  const float* x = (const float*)d_in[0];
  const int* ei = (const int*)d_in[1];      // [2, NE]: src row then dst row
  const float* eattr = (const float*)d_in[2];

  char* w = (char*)d_ws;
  int* degi      = (int*)w;                 w += NN * 4;
  int* cursor    = (int*)w;                 w += NN * 4;
  int* rowptr    = (int*)w;                 w += (NN + 1) * 4;
  int* csr_eid   = (int*)w;                 w += NE * 4;
  int* csr_src   = (int*)w;                 w += NE * 4;
  int* csr_dst   = (int*)w;                 w += NE * 4;
  float* loop_attr = (float*)w;             w += (size_t)NN * ED * 4;
  float* ea_csr  = (float*)w;               w += (size_t)EF * ED * 4;
  float* xl      = (float*)w;               w += (size_t)NN * HC * 4;
  float* scoreP  = (float*)w;               w += (size_t)NH * EF * 4;
  float* partial = (float*)w;               w += (size_t)NN * NH * CD * 4;
  float* hbuf    = (float*)w;               w += (size_t)NN * CD * 4;

  // graph structure + permuted edge attrs (layer-invariant)
  hipMemsetAsync(degi, 0, NN * 4, stream);
  hipMemsetAsync(cursor, 0, NN * 4, stream);
  k_count<<<(NE + 255) / 256, 256, 0, stream>>>(ei + NE, degi);
  k_scan<<<1, 256, 0, stream>>>(degi, rowptr);
  k_fill<<<(NE + 255) / 256, 256, 0, stream>>>(ei, rowptr, cursor, csr_eid, csr_src, csr_dst);
  k_loopattr<<<(NN + 3) / 4, 256, 0, stream>>>(csr_eid, rowptr, eattr, loop_attr);
  k_eacsr<<<(EF * 4 + 255) / 256, 256, 0, stream>>>(csr_eid, eattr, loop_attr, ea_csr);

  for (int l = 0; l < 3; l++) {
    const float* Wl  = (const float*)d_in[3 + 5 * l];
    const float* bl  = (const float*)d_in[4 + 5 * l];
    const float* We  = (const float*)d_in[5 + 5 * l];
    const float* att = (const float*)d_in[6 + 5 * l];
    const float* b   = (const float*)d_in[7 + 5 * l];

    if (l == 0) k_xl<ND><<<NN / 8, 320, 0, stream>>>(x, Wl, bl, xl);
    else        k_xl<CD><<<NN / 8, 320, 0, stream>>>(hbuf, Wl, bl, xl);

    dim3 gs(GX, NH);
    k_score<<<gs, 256, 0, stream>>>(csr_src, csr_dst, ea_csr, xl, We, att, scoreP);

    dim3 gg((NN + 3) / 4, NH);
    k_gat<<<gg, 256, 0, stream>>>(csr_src, rowptr, scoreP, xl, partial);

    float* dst_out = (l < 2) ? hbuf : (float*)d_out;
    k_comb<<<(NN * CD + 255) / 256, 256, 0, stream>>>(partial, b, dst_out);
  }
}

// Round 5
// 734.204 us; speedup vs baseline: 1.5977x; 1.5977x over previous
//
#include <hip/hip_runtime.h>
#include <hip/hip_bf16.h>

// GATv2 x3 layers, MI355X. f32 in/out; edge_index int32.
// R5: wave-per-edge score kernel (round-3 MLP) with We hoisted into 80 VGPRs
// per lane (zero LDS traffic). CSR-ordered edges, pre-permuted edge attrs,
// scores [head][pos] for coalesced softmax, (node,head)-parallel aggregate.

#define NN 10000    // nodes
#define NE 200000   // edges
#define ND 128      // node dim (layer 0 input)
#define ED 16       // edge dim
#define CD 64       // conv dim (per head)
#define NH 5        // heads
#define HC 320      // NH*CD
#define EF 210000   // NE + NN (with self loops)
#define NEG 0.2f
#define GX 2048     // k_score blocks
#define CH 26       // edges per wave: 2048*4*26 >= EF

// ---- CSR build: count ----
__global__ void k_count(const int* __restrict__ dst, int* __restrict__ deg) {
  int e = blockIdx.x * blockDim.x + threadIdx.x;
  if (e >= NE) return;
  atomicAdd(&deg[dst[e]], 1);
}

// ---- CSR build: exclusive scan (single block) ----
__global__ __launch_bounds__(256) void k_scan(const int* __restrict__ deg,
                                              int* __restrict__ rowptr) {
  __shared__ int part[256];
  int t = threadIdx.x;
  int base = t * 40;
  int local[40];
  int s = 0;
  #pragma unroll
  for (int j = 0; j < 40; j++) {
    int i = base + j;
    local[j] = (i < NN) ? deg[i] : 0;
    s += local[j];
  }
  part[t] = s;
  __syncthreads();
  for (int off = 1; off < 256; off <<= 1) {
    int v = (t >= off) ? part[t - off] : 0;
    __syncthreads();
    part[t] += v;
    __syncthreads();
  }
  int prefix = (t > 0) ? part[t - 1] : 0;
  #pragma unroll
  for (int j = 0; j < 40; j++) {
    int i = base + j;
    if (i < NN) rowptr[i] = prefix;
    prefix += local[j];
  }
  if (t == 255) rowptr[NN] = prefix;
}

// ---- CSR build: fill ----
__global__ void k_fill(const int* __restrict__ ei, const int* __restrict__ rowptr,
                       int* __restrict__ cursor, int* __restrict__ csr_eid,
                       int* __restrict__ csr_src, int* __restrict__ csr_dst) {
  int e = blockIdx.x * blockDim.x + threadIdx.x;
  if (e >= NE) return;
  int d = ei[NE + e];
  int slot = atomicAdd(&cursor[d], 1);
  int pos = rowptr[d] + slot;
  csr_eid[pos] = e;
  csr_src[pos] = ei[e];
  csr_dst[pos] = d;
}

// ---- loop_attr = mean of incoming edge_attr (gather, wave per node) ----
__global__ __launch_bounds__(256) void k_loopattr(const int* __restrict__ csr_eid,
                                                  const int* __restrict__ rowptr,
                                                  const float* __restrict__ eattr,
                                                  float* __restrict__ loop_attr) {
  int wave = threadIdx.x >> 6, lane = threadIdx.x & 63;
  int d = blockIdx.x * 4 + wave;
  if (d >= NN) return;
  int g = lane >> 4, k = lane & 15;
  int b = rowptr[d], n = rowptr[d + 1] - b;
  float s = 0.f;
  for (int i = g; i < n; i += 4)
    s += eattr[(size_t)csr_eid[b + i] * ED + k];
  s += __shfl_xor(s, 16, 64);
  s += __shfl_xor(s, 32, 64);
  if (g == 0) loop_attr[d * ED + k] = s / fmaxf((float)n, 1.0f);
}

// ---- ea_csr[p] = edge attrs in CSR order; self-loop attrs appended ----
__global__ void k_eacsr(const int* __restrict__ csr_eid, const float* __restrict__ eattr,
                        const float* __restrict__ loop_attr, float* __restrict__ ea_csr) {
  int idx = blockIdx.x * blockDim.x + threadIdx.x;  // (p, quad)
  if (idx >= EF * 4) return;
  int p = idx >> 2, q = idx & 3;
  const float4* sp;
  if (p < NE) sp = (const float4*)(eattr + (size_t)csr_eid[p] * ED);
  else        sp = (const float4*)(loop_attr + (size_t)(p - NE) * ED);
  ((float4*)(ea_csr + (size_t)p * ED))[q] = sp[q];
}

// ---- xl = h @ Wl + bl  (no LDS; h rows via uniform broadcast loads) ----
template <int D>
__global__ __launch_bounds__(320) void k_xl(const float* __restrict__ h,
                                            const float* __restrict__ Wl,
                                            const float* __restrict__ bl,
                                            float* __restrict__ xl) {
  constexpr int NPB = 8;
  int node0 = blockIdx.x * NPB;
  int t = threadIdx.x;  // output column 0..319
  float acc[NPB];
  #pragma unroll
  for (int i = 0; i < NPB; i++) acc[i] = 0.f;
  for (int k = 0; k < D; k += 4) {
    float w0 = Wl[(k + 0) * HC + t];
    float w1 = Wl[(k + 1) * HC + t];
    float w2 = Wl[(k + 2) * HC + t];
    float w3 = Wl[(k + 3) * HC + t];
    #pragma unroll
    for (int i = 0; i < NPB; i++) {
      float4 hv = *(const float4*)(h + (size_t)(node0 + i) * D + k);
      acc[i] += hv.x * w0 + hv.y * w1 + hv.z * w2 + hv.w * w3;
    }
  }
  float bv = bl[t];
  #pragma unroll
  for (int i = 0; i < NPB; i++)
    xl[(size_t)(node0 + i) * HC + t] = acc[i] + bv;
}

// ---- scores: wave per edge, all 5 heads; We slice in 80 VGPRs ----
__global__ __launch_bounds__(256) void k_score(
    const int* __restrict__ csr_src, const int* __restrict__ csr_dst,
    const float* __restrict__ ea_csr, const float* __restrict__ xl,
    const float* __restrict__ We, const float* __restrict__ att,
    float* __restrict__ scoreP) {
  int lane = threadIdx.x & 63, w = threadIdx.x >> 6;
  int wid = blockIdx.x * 4 + w;
  // hoist We column slice + att: lane c holds We[k, h*CD+c] for all k,h
  float Wr[ED][NH];
  #pragma unroll
  for (int k = 0; k < ED; k++)
    #pragma unroll
    for (int h = 0; h < NH; h++)
      Wr[k][h] = We[k * HC + h * CD + lane];
  float attv[NH];
  #pragma unroll
  for (int h = 0; h < NH; h++) attv[h] = att[h * CD + lane];

  int p0 = wid * CH, p1 = min(p0 + CH, EF);
  for (int p = p0; p < p1; p++) {
    int s, d;
    if (p < NE) { s = csr_src[p]; d = csr_dst[p]; }
    else        { s = d = p - NE; }
    const float4* eap = (const float4*)(ea_csr + (size_t)p * ED);
    float4 e0 = eap[0], e1 = eap[1], e2 = eap[2], e3 = eap[3];
    const float* xs = xl + (size_t)s * HC + lane;
    const float* xd = xl + (size_t)d * HC + lane;
    float sc[NH];
    #pragma unroll
    for (int h = 0; h < NH; h++) {
      float v = xs[h * CD] + xd[h * CD];
      v += e0.x * Wr[0][h]  + e0.y * Wr[1][h]  + e0.z * Wr[2][h]  + e0.w * Wr[3][h];
      v += e1.x * Wr[4][h]  + e1.y * Wr[5][h]  + e1.z * Wr[6][h]  + e1.w * Wr[7][h];
      v += e2.x * Wr[8][h]  + e2.y * Wr[9][h]  + e2.z * Wr[10][h] + e2.w * Wr[11][h];
      v += e3.x * Wr[12][h] + e3.y * Wr[13][h] + e3.z * Wr[14][h] + e3.w * Wr[15][h];
      v = v > 0.f ? v : NEG * v;
      sc[h] = v * attv[h];
    }
    #pragma unroll
    for (int off = 1; off < 64; off <<= 1) {
      #pragma unroll
      for (int h = 0; h < NH; h++) sc[h] += __shfl_xor(sc[h], off, 64);
    }
    if (lane == 0) {
      #pragma unroll
      for (int h = 0; h < NH; h++) scoreP[(size_t)h * EF + p] = sc[h];
    }
  }
}

// ---- softmax + aggregate per (node, head); partial[d][h][c] out ----
__global__ __launch_bounds__(256) void k_gat(const int* __restrict__ csr_src,
                                             const int* __restrict__ rowptr,
                                             const float* __restrict__ scoreP,
                                             const float* __restrict__ xl,
                                             float* __restrict__ partial) {
  int w = threadIdx.x >> 6, lane = threadIdx.x & 63;
  int d = blockIdx.x * 4 + w;
  int h = blockIdx.y;
  if (d >= NN) return;
  int b = rowptr[d], n = rowptr[d + 1] - b;  // + self loop at pos NE+d
  const float* sp = scoreP + (size_t)h * EF;
  // max (contiguous sp[b..b+n) + self loop)
  float m = sp[NE + d];
  for (int i = lane; i < n; i += 64) m = fmaxf(m, sp[b + i]);
  #pragma unroll
  for (int off = 1; off < 64; off <<= 1) m = fmaxf(m, __shfl_xor(m, off, 64));
  // denom
  float dn = (lane == 0) ? __expf(sp[NE + d] - m) : 0.f;
  for (int i = lane; i < n; i += 64) dn += __expf(sp[b + i] - m);
  #pragma unroll
  for (int off = 1; off < 64; off <<= 1) dn += __shfl_xor(dn, off, 64);
  float rdn = 1.0f / dn;
  const float* xh = xl + h * CD + lane;
  // self loop contribution
  float acc = __expf(sp[NE + d] - m) * rdn * xh[(size_t)d * HC];
  // real edges, unroll 2 for MLP
  int i = 0;
  for (; i + 2 <= n; i += 2) {
    int s0 = csr_src[b + i], s1 = csr_src[b + i + 1];
    float a0 = __expf(sp[b + i] - m) * rdn;
    float a1 = __expf(sp[b + i + 1] - m) * rdn;
    acc += a0 * xh[(size_t)s0 * HC] + a1 * xh[(size_t)s1 * HC];
  }
  if (i < n) {
    int s0 = csr_src[b + i];
    acc += __expf(sp[b + i] - m) * rdn * xh[(size_t)s0 * HC];
  }
  partial[((size_t)d * NH + h) * CD + lane] = acc;
}

// ---- combine heads + bias + elu ----
__global__ void k_comb(const float* __restrict__ partial, const float* __restrict__ bias,
                       float* __restrict__ out) {
  int i = blockIdx.x * blockDim.x + threadIdx.x;
  if (i >= NN * CD) return;
  int d = i >> 6, c = i & 63;
  float v = 0.f;
  #pragma unroll
  for (int h = 0; h < NH; h++) v += partial[((size_t)d * NH + h) * CD + c];
  v = v * (1.0f / NH) + bias[c];
  v = v > 0.f ? v : expm1f(v);
  out[i] = v;
}

extern "C" void kernel_launch(void* const* d_in, const int* in_sizes, int n_in,
                              void* d_out, int out_size, void* d_ws, size_t ws_size,
                              hipStream_t stream) {
  const float* x = (const float*)d_in[0];
  const int* ei = (const int*)d_in[1];      // [2, NE]: src row then dst row
  const float* eattr = (const float*)d_in[2];

  char* w = (char*)d_ws;
  int* degi      = (int*)w;                 w += NN * 4;
  int* cursor    = (int*)w;                 w += NN * 4;
  int* rowptr    = (int*)w;                 w += (NN + 1) * 4;
  int* csr_eid   = (int*)w;                 w += NE * 4;
  int* csr_src   = (int*)w;                 w += NE * 4;
  int* csr_dst   = (int*)w;                 w += NE * 4;
  float* loop_attr = (float*)w;             w += (size_t)NN * ED * 4;
  float* ea_csr  = (float*)w;               w += (size_t)EF * ED * 4;
  float* xl      = (float*)w;               w += (size_t)NN * HC * 4;
  float* scoreP  = (float*)w;               w += (size_t)NH * EF * 4;
  float* partial = (float*)w;               w += (size_t)NN * NH * CD * 4;
  float* hbuf    = (float*)w;               w += (size_t)NN * CD * 4;

  // graph structure + permuted edge attrs (layer-invariant)
  hipMemsetAsync(degi, 0, NN * 4, stream);
  hipMemsetAsync(cursor, 0, NN * 4, stream);
  k_count<<<(NE + 255) / 256, 256, 0, stream>>>(ei + NE, degi);
  k_scan<<<1, 256, 0, stream>>>(degi, rowptr);
  k_fill<<<(NE + 255) / 256, 256, 0, stream>>>(ei, rowptr, cursor, csr_eid, csr_src, csr_dst);
  k_loopattr<<<(NN + 3) / 4, 256, 0, stream>>>(csr_eid, rowptr, eattr, loop_attr);
  k_eacsr<<<(EF * 4 + 255) / 256, 256, 0, stream>>>(csr_eid, eattr, loop_attr, ea_csr);

  for (int l = 0; l < 3; l++) {
    const float* Wl  = (const float*)d_in[3 + 5 * l];
    const float* bl  = (const float*)d_in[4 + 5 * l];
    const float* We  = (const float*)d_in[5 + 5 * l];
    const float* att = (const float*)d_in[6 + 5 * l];
    const float* b   = (const float*)d_in[7 + 5 * l];

    if (l == 0) k_xl<ND><<<NN / 8, 320, 0, stream>>>(x, Wl, bl, xl);
    else        k_xl<CD><<<NN / 8, 320, 0, stream>>>(hbuf, Wl, bl, xl);

    k_score<<<GX, 256, 0, stream>>>(csr_src, csr_dst, ea_csr, xl, We, att, scoreP);

    dim3 gg((NN + 3) / 4, NH);
    k_gat<<<gg, 256, 0, stream>>>(csr_src, rowptr, scoreP, xl, partial);

    float* dst_out = (l < 2) ? hbuf : (float*)d_out;
    k_comb<<<(NN * CD + 255) / 256, 256, 0, stream>>>(partial, b, dst_out);
  }
}

// Round 6
// 682.642 us; speedup vs baseline: 1.7184x; 1.0755x over previous
//
#include <hip/hip_runtime.h>
#include <hip/hip_bf16.h>

// GATv2 x3 layers, MI355X. f32 in/out; edge_index int32.
// R6: fused per-dst kernel — score + online softmax + aggregation + head-mean
// + bias + ELU in ONE pass over each node's CSR edge list. xl[src] gathered
// once per edge (was twice: k_score + k_gat); xl[dst] hoisted per row;
// scoreP/partial buffers eliminated.

#define NN 10000    // nodes
#define NE 200000   // edges
#define ND 128      // node dim (layer 0 input)
#define ED 16       // edge dim
#define CD 64       // conv dim (per head)
#define NH 5        // heads
#define HC 320      // NH*CD
#define NEG 0.2f

// ---- CSR build: count ----
__global__ void k_count(const int* __restrict__ dst, int* __restrict__ deg) {
  int e = blockIdx.x * blockDim.x + threadIdx.x;
  if (e >= NE) return;
  atomicAdd(&deg[dst[e]], 1);
}

// ---- CSR build: exclusive scan (single block) ----
__global__ __launch_bounds__(256) void k_scan(const int* __restrict__ deg,
                                              int* __restrict__ rowptr) {
  __shared__ int part[256];
  int t = threadIdx.x;
  int base = t * 40;
  int local[40];
  int s = 0;
  #pragma unroll
  for (int j = 0; j < 40; j++) {
    int i = base + j;
    local[j] = (i < NN) ? deg[i] : 0;
    s += local[j];
  }
  part[t] = s;
  __syncthreads();
  for (int off = 1; off < 256; off <<= 1) {
    int v = (t >= off) ? part[t - off] : 0;
    __syncthreads();
    part[t] += v;
    __syncthreads();
  }
  int prefix = (t > 0) ? part[t - 1] : 0;
  #pragma unroll
  for (int j = 0; j < 40; j++) {
    int i = base + j;
    if (i < NN) rowptr[i] = prefix;
    prefix += local[j];
  }
  if (t == 255) rowptr[NN] = prefix;
}

// ---- CSR build: fill ----
__global__ void k_fill(const int* __restrict__ ei, const int* __restrict__ rowptr,
                       int* __restrict__ cursor, int* __restrict__ csr_eid,
                       int* __restrict__ csr_src) {
  int e = blockIdx.x * blockDim.x + threadIdx.x;
  if (e >= NE) return;
  int d = ei[NE + e];
  int slot = atomicAdd(&cursor[d], 1);
  int pos = rowptr[d] + slot;
  csr_eid[pos] = e;
  csr_src[pos] = ei[e];
}

// ---- loop_attr = mean of incoming edge_attr (gather, wave per node) ----
__global__ __launch_bounds__(256) void k_loopattr(const int* __restrict__ csr_eid,
                                                  const int* __restrict__ rowptr,
                                                  const float* __restrict__ eattr,
                                                  float* __restrict__ loop_attr) {
  int wave = threadIdx.x >> 6, lane = threadIdx.x & 63;
  int d = blockIdx.x * 4 + wave;
  if (d >= NN) return;
  int g = lane >> 4, k = lane & 15;
  int b = rowptr[d], n = rowptr[d + 1] - b;
  float s = 0.f;
  for (int i = g; i < n; i += 4)
    s += eattr[(size_t)csr_eid[b + i] * ED + k];
  s += __shfl_xor(s, 16, 64);
  s += __shfl_xor(s, 32, 64);
  if (g == 0) loop_attr[d * ED + k] = s / fmaxf((float)n, 1.0f);
}

// ---- ea_csr[p] = edge attrs permuted into CSR order (real edges only) ----
__global__ void k_eacsr(const int* __restrict__ csr_eid, const float* __restrict__ eattr,
                        float* __restrict__ ea_csr) {
  int idx = blockIdx.x * blockDim.x + threadIdx.x;  // (p, quad)
  if (idx >= NE * 4) return;
  int p = idx >> 2, q = idx & 3;
  const float4* sp = (const float4*)(eattr + (size_t)csr_eid[p] * ED);
  ((float4*)(ea_csr + (size_t)p * ED))[q] = sp[q];
}

// ---- xl = h @ Wl + bl  (no LDS; h rows via uniform broadcast loads) ----
template <int D>
__global__ __launch_bounds__(320) void k_xl(const float* __restrict__ h,
                                            const float* __restrict__ Wl,
                                            const float* __restrict__ bl,
                                            float* __restrict__ xl) {
  constexpr int NPB = 8;
  int node0 = blockIdx.x * NPB;
  int t = threadIdx.x;  // output column 0..319
  float acc[NPB];
  #pragma unroll
  for (int i = 0; i < NPB; i++) acc[i] = 0.f;
  for (int k = 0; k < D; k += 4) {
    float w0 = Wl[(k + 0) * HC + t];
    float w1 = Wl[(k + 1) * HC + t];
    float w2 = Wl[(k + 2) * HC + t];
    float w3 = Wl[(k + 3) * HC + t];
    #pragma unroll
    for (int i = 0; i < NPB; i++) {
      float4 hv = *(const float4*)(h + (size_t)(node0 + i) * D + k);
      acc[i] += hv.x * w0 + hv.y * w1 + hv.z * w2 + hv.w * w3;
    }
  }
  float bv = bl[t];
  #pragma unroll
  for (int i = 0; i < NPB; i++)
    xl[(size_t)(node0 + i) * HC + t] = acc[i] + bv;
}

// ---- fused GATv2: wave per dst node; online softmax over incoming edges ----
__global__ __launch_bounds__(256) void k_fused(
    const int* __restrict__ csr_src, const int* __restrict__ rowptr,
    const float* __restrict__ ea_csr, const float* __restrict__ loop_attr,
    const float* __restrict__ xl, const float* __restrict__ We,
    const float* __restrict__ att, const float* __restrict__ bias,
    float* __restrict__ out) {
  int w = threadIdx.x >> 6, lane = threadIdx.x & 63;
  int d = blockIdx.x * 4 + w;
  if (d >= NN) return;

  // per-lane We column slice + att (uniform per wave, L1-resident)
  float Wr[ED][NH];
  #pragma unroll
  for (int k = 0; k < ED; k++)
    #pragma unroll
    for (int h = 0; h < NH; h++)
      Wr[k][h] = We[k * HC + h * CD + lane];
  float attv[NH];
  #pragma unroll
  for (int h = 0; h < NH; h++) attv[h] = att[h * CD + lane];

  int p0 = rowptr[d], p1 = rowptr[d + 1];  // real edges; p==p1 => self loop
  float xd[NH];
  #pragma unroll
  for (int h = 0; h < NH; h++) xd[h] = xl[(size_t)d * HC + h * CD + lane];

  float m[NH], l[NH], acc[NH];
  #pragma unroll
  for (int h = 0; h < NH; h++) { m[h] = -1e30f; l[h] = 0.f; acc[h] = 0.f; }

  // software-pipeline registers (next edge)
  float4 ea0, ea1, ea2, ea3;
  float xs[NH];
#define LOAD_EDGE(p)                                                      \
  {                                                                       \
    int s_;                                                               \
    const float4* eap_;                                                   \
    if ((p) < p1) { s_ = csr_src[p]; eap_ = (const float4*)(ea_csr + (size_t)(p) * ED); } \
    else          { s_ = d;          eap_ = (const float4*)(loop_attr + (size_t)d * ED); } \
    ea0 = eap_[0]; ea1 = eap_[1]; ea2 = eap_[2]; ea3 = eap_[3];           \
    _Pragma("unroll")                                                     \
    for (int h = 0; h < NH; h++) xs[h] = xl[(size_t)s_ * HC + h * CD + lane]; \
  }

  LOAD_EDGE(p0);
  for (int p = p0; p <= p1; p++) {
    // snapshot current edge
    float4 c0 = ea0, c1 = ea1, c2 = ea2, c3 = ea3;
    float cx[NH];
    #pragma unroll
    for (int h = 0; h < NH; h++) cx[h] = xs[h];
    if (p + 1 <= p1) LOAD_EDGE(p + 1);  // prefetch overlaps compute below

    float sc[NH];
    #pragma unroll
    for (int h = 0; h < NH; h++) {
      float v = cx[h] + xd[h];
      v += c0.x * Wr[0][h]  + c0.y * Wr[1][h]  + c0.z * Wr[2][h]  + c0.w * Wr[3][h];
      v += c1.x * Wr[4][h]  + c1.y * Wr[5][h]  + c1.z * Wr[6][h]  + c1.w * Wr[7][h];
      v += c2.x * Wr[8][h]  + c2.y * Wr[9][h]  + c2.z * Wr[10][h] + c2.w * Wr[11][h];
      v += c3.x * Wr[12][h] + c3.y * Wr[13][h] + c3.z * Wr[14][h] + c3.w * Wr[15][h];
      v = v > 0.f ? v : NEG * v;
      sc[h] = v * attv[h];
    }
    #pragma unroll
    for (int off = 1; off < 64; off <<= 1) {
      #pragma unroll
      for (int h = 0; h < NH; h++) sc[h] += __shfl_xor(sc[h], off, 64);
    }
    // online softmax update (per head)
    #pragma unroll
    for (int h = 0; h < NH; h++) {
      float mn = fmaxf(m[h], sc[h]);
      float r0 = __expf(m[h] - mn);
      float r1 = __expf(sc[h] - mn);
      l[h]   = l[h] * r0 + r1;
      acc[h] = acc[h] * r0 + r1 * cx[h];
      m[h] = mn;
    }
  }
#undef LOAD_EDGE

  float v = 0.f;
  #pragma unroll
  for (int h = 0; h < NH; h++) v += acc[h] / l[h];
  v = v * (1.0f / NH) + bias[lane];
  v = v > 0.f ? v : expm1f(v);
  out[(size_t)d * CD + lane] = v;
}

extern "C" void kernel_launch(void* const* d_in, const int* in_sizes, int n_in,
                              void* d_out, int out_size, void* d_ws, size_t ws_size,
                              hipStream_t stream) {
  const float* x = (const float*)d_in[0];
  const int* ei = (const int*)d_in[1];      // [2, NE]: src row then dst row
  const float* eattr = (const float*)d_in[2];

  char* w = (char*)d_ws;
  int* degi      = (int*)w;                 w += NN * 4;
  int* cursor    = (int*)w;                 w += NN * 4;
  int* rowptr    = (int*)w;                 w += (NN + 1) * 4;
  int* csr_eid   = (int*)w;                 w += NE * 4;
  int* csr_src   = (int*)w;                 w += NE * 4;
  float* loop_attr = (float*)w;             w += (size_t)NN * ED * 4;
  float* ea_csr  = (float*)w;               w += (size_t)NE * ED * 4;
  float* xl      = (float*)w;               w += (size_t)NN * HC * 4;
  float* hbuf    = (float*)w;               w += (size_t)NN * CD * 4;

  // graph structure + permuted edge attrs (layer-invariant)
  hipMemsetAsync(degi, 0, NN * 4, stream);
  hipMemsetAsync(cursor, 0, NN * 4, stream);
  k_count<<<(NE + 255) / 256, 256, 0, stream>>>(ei + NE, degi);
  k_scan<<<1, 256, 0, stream>>>(degi, rowptr);
  k_fill<<<(NE + 255) / 256, 256, 0, stream>>>(ei, rowptr, cursor, csr_eid, csr_src);
  k_loopattr<<<(NN + 3) / 4, 256, 0, stream>>>(csr_eid, rowptr, eattr, loop_attr);
  k_eacsr<<<(NE * 4 + 255) / 256, 256, 0, stream>>>(csr_eid, eattr, ea_csr);

  for (int l = 0; l < 3; l++) {
    const float* Wl  = (const float*)d_in[3 + 5 * l];
    const float* bl  = (const float*)d_in[4 + 5 * l];
    const float* We  = (const float*)d_in[5 + 5 * l];
    const float* att = (const float*)d_in[6 + 5 * l];
    const float* b   = (const float*)d_in[7 + 5 * l];

    if (l == 0) k_xl<ND><<<NN / 8, 320, 0, stream>>>(x, Wl, bl, xl);
    else        k_xl<CD><<<NN / 8, 320, 0, stream>>>(hbuf, Wl, bl, xl);

    float* dst_out = (l < 2) ? hbuf : (float*)d_out;
    k_fused<<<(NN + 3) / 4, 256, 0, stream>>>(csr_src, rowptr, ea_csr, loop_attr,
                                              xl, We, att, b, dst_out);
  }
}

// Round 7
// 601.280 us; speedup vs baseline: 1.9509x; 1.1353x over previous
//
#include <hip/hip_runtime.h>
#include <hip/hip_bf16.h>

// GATv2 x3 layers, MI355X. f32 in/out; edge_index int32.
// R7: fused per-dst kernel, self-loop peeled (zero conditionals in loop),
// unroll-by-2 with named regs (10 independent shfl trees, batched online
// update), int32 addressing. xl[src] read once per edge, no score buffers.

#define NN 10000    // nodes
#define NE 200000   // edges
#define ND 128      // node dim (layer 0 input)
#define ED 16       // edge dim
#define CD 64       // conv dim (per head)
#define NH 5        // heads
#define HC 320      // NH*CD
#define NEG 0.2f

// ---- CSR build: count ----
__global__ void k_count(const int* __restrict__ dst, int* __restrict__ deg) {
  int e = blockIdx.x * blockDim.x + threadIdx.x;
  if (e >= NE) return;
  atomicAdd(&deg[dst[e]], 1);
}

// ---- CSR build: exclusive scan (single block) ----
__global__ __launch_bounds__(256) void k_scan(const int* __restrict__ deg,
                                              int* __restrict__ rowptr) {
  __shared__ int part[256];
  int t = threadIdx.x;
  int base = t * 40;
  int local[40];
  int s = 0;
  #pragma unroll
  for (int j = 0; j < 40; j++) {
    int i = base + j;
    local[j] = (i < NN) ? deg[i] : 0;
    s += local[j];
  }
  part[t] = s;
  __syncthreads();
  for (int off = 1; off < 256; off <<= 1) {
    int v = (t >= off) ? part[t - off] : 0;
    __syncthreads();
    part[t] += v;
    __syncthreads();
  }
  int prefix = (t > 0) ? part[t - 1] : 0;
  #pragma unroll
  for (int j = 0; j < 40; j++) {
    int i = base + j;
    if (i < NN) rowptr[i] = prefix;
    prefix += local[j];
  }
  if (t == 255) rowptr[NN] = prefix;
}

// ---- CSR build: fill ----
__global__ void k_fill(const int* __restrict__ ei, const int* __restrict__ rowptr,
                       int* __restrict__ cursor, int* __restrict__ csr_eid,
                       int* __restrict__ csr_src) {
  int e = blockIdx.x * blockDim.x + threadIdx.x;
  if (e >= NE) return;
  int d = ei[NE + e];
  int slot = atomicAdd(&cursor[d], 1);
  int pos = rowptr[d] + slot;
  csr_eid[pos] = e;
  csr_src[pos] = ei[e];
}

// ---- loop_attr = mean of incoming edge_attr (gather, wave per node) ----
__global__ __launch_bounds__(256) void k_loopattr(const int* __restrict__ csr_eid,
                                                  const int* __restrict__ rowptr,
                                                  const float* __restrict__ eattr,
                                                  float* __restrict__ loop_attr) {
  int wave = threadIdx.x >> 6, lane = threadIdx.x & 63;
  int d = blockIdx.x * 4 + wave;
  if (d >= NN) return;
  int g = lane >> 4, k = lane & 15;
  int b = rowptr[d], n = rowptr[d + 1] - b;
  float s = 0.f;
  for (int i = g; i < n; i += 4)
    s += eattr[(size_t)csr_eid[b + i] * ED + k];
  s += __shfl_xor(s, 16, 64);
  s += __shfl_xor(s, 32, 64);
  if (g == 0) loop_attr[d * ED + k] = s / fmaxf((float)n, 1.0f);
}

// ---- ea_csr[p] = edge attrs permuted into CSR order (real edges only) ----
__global__ void k_eacsr(const int* __restrict__ csr_eid, const float* __restrict__ eattr,
                        float* __restrict__ ea_csr) {
  int idx = blockIdx.x * blockDim.x + threadIdx.x;  // (p, quad)
  if (idx >= NE * 4) return;
  int p = idx >> 2, q = idx & 3;
  const float4* sp = (const float4*)(eattr + (size_t)csr_eid[p] * ED);
  ((float4*)(ea_csr + (size_t)p * ED))[q] = sp[q];
}

// ---- xl = h @ Wl + bl  (no LDS; h rows via uniform broadcast loads) ----
template <int D>
__global__ __launch_bounds__(320) void k_xl(const float* __restrict__ h,
                                            const float* __restrict__ Wl,
                                            const float* __restrict__ bl,
                                            float* __restrict__ xl) {
  constexpr int NPB = 8;
  int node0 = blockIdx.x * NPB;
  int t = threadIdx.x;  // output column 0..319
  float acc[NPB];
  #pragma unroll
  for (int i = 0; i < NPB; i++) acc[i] = 0.f;
  for (int k = 0; k < D; k += 4) {
    float w0 = Wl[(k + 0) * HC + t];
    float w1 = Wl[(k + 1) * HC + t];
    float w2 = Wl[(k + 2) * HC + t];
    float w3 = Wl[(k + 3) * HC + t];
    #pragma unroll
    for (int i = 0; i < NPB; i++) {
      float4 hv = *(const float4*)(h + (size_t)(node0 + i) * D + k);
      acc[i] += hv.x * w0 + hv.y * w1 + hv.z * w2 + hv.w * w3;
    }
  }
  float bv = bl[t];
  #pragma unroll
  for (int i = 0; i < NPB; i++)
    xl[(size_t)(node0 + i) * HC + t] = acc[i] + bv;
}

// score for one edge: v_c = leakyrelu(xs+xd+ea.We); sc_h = v*att (pre-reduce)
#define SCORE1(E0, E1, E2, E3, XS, SC)                                        \
  _Pragma("unroll")                                                           \
  for (int h = 0; h < NH; h++) {                                              \
    float v = XS[h] + xd[h];                                                  \
    v += E0.x * Wr[0][h]  + E0.y * Wr[1][h]  + E0.z * Wr[2][h]  + E0.w * Wr[3][h];  \
    v += E1.x * Wr[4][h]  + E1.y * Wr[5][h]  + E1.z * Wr[6][h]  + E1.w * Wr[7][h];  \
    v += E2.x * Wr[8][h]  + E2.y * Wr[9][h]  + E2.z * Wr[10][h] + E2.w * Wr[11][h]; \
    v += E3.x * Wr[12][h] + E3.y * Wr[13][h] + E3.z * Wr[14][h] + E3.w * Wr[15][h]; \
    v = fmaxf(v, 0.f) + NEG * fminf(v, 0.f);                                  \
    SC[h] = v * attv[h];                                                      \
  }

// ---- fused GATv2: wave per dst node; online softmax; unroll-2 ----
__global__ __launch_bounds__(256) void k_fused(
    const int* __restrict__ csr_src, const int* __restrict__ rowptr,
    const float* __restrict__ ea_csr, const float* __restrict__ loop_attr,
    const float* __restrict__ xl, const float* __restrict__ We,
    const float* __restrict__ att, const float* __restrict__ bias,
    float* __restrict__ out) {
  int w = threadIdx.x >> 6, lane = threadIdx.x & 63;
  int d = blockIdx.x * 4 + w;
  if (d >= NN) return;

  const float* xlL = xl + lane;  // per-lane base; h*CD folds into load immediates

  float Wr[ED][NH];
  #pragma unroll
  for (int k = 0; k < ED; k++)
    #pragma unroll
    for (int h = 0; h < NH; h++)
      Wr[k][h] = We[k * HC + h * CD + lane];
  float attv[NH];
  #pragma unroll
  for (int h = 0; h < NH; h++) attv[h] = att[h * CD + lane];

  int bd = d * HC;
  float xd[NH];
  #pragma unroll
  for (int h = 0; h < NH; h++) xd[h] = xlL[bd + h * CD];

  // ---- self loop (peeled): init online state ----
  const float4* lap = (const float4*)(loop_attr + d * ED);
  float4 a0 = lap[0], a1 = lap[1], a2 = lap[2], a3 = lap[3];
  float scS[NH];
  SCORE1(a0, a1, a2, a3, xd, scS);
  #pragma unroll
  for (int off = 1; off < 64; off <<= 1) {
    #pragma unroll
    for (int h = 0; h < NH; h++) scS[h] += __shfl_xor(scS[h], off, 64);
  }
  float m[NH], l[NH], acc[NH];
  #pragma unroll
  for (int h = 0; h < NH; h++) { m[h] = scS[h]; l[h] = 1.f; acc[h] = xd[h]; }

  int p0 = rowptr[d], p1 = rowptr[d + 1];
  int p = p0;
  for (; p + 2 <= p1; p += 2) {
    int s0 = csr_src[p], s1 = csr_src[p + 1];
    const float4* q = (const float4*)ea_csr + p * 4;
    float4 e00 = q[0], e01 = q[1], e02 = q[2], e03 = q[3];
    float4 e10 = q[4], e11 = q[5], e12 = q[6], e13 = q[7];
    int b0 = s0 * HC, b1 = s1 * HC;
    float xs0[NH], xs1[NH];
    #pragma unroll
    for (int h = 0; h < NH; h++) { xs0[h] = xlL[b0 + h * CD]; xs1[h] = xlL[b1 + h * CD]; }

    float sc0[NH], sc1[NH];
    SCORE1(e00, e01, e02, e03, xs0, sc0);
    SCORE1(e10, e11, e12, e13, xs1, sc1);
    #pragma unroll
    for (int off = 1; off < 64; off <<= 1) {
      #pragma unroll
      for (int h = 0; h < NH; h++) {
        sc0[h] += __shfl_xor(sc0[h], off, 64);
        sc1[h] += __shfl_xor(sc1[h], off, 64);
      }
    }
    #pragma unroll
    for (int h = 0; h < NH; h++) {
      float mn = fmaxf(m[h], fmaxf(sc0[h], sc1[h]));
      float r  = __expf(m[h] - mn);
      float g0 = __expf(sc0[h] - mn);
      float g1 = __expf(sc1[h] - mn);
      l[h]   = l[h] * r + g0 + g1;
      acc[h] = acc[h] * r + g0 * xs0[h] + g1 * xs1[h];
      m[h] = mn;
    }
  }
  if (p < p1) {  // odd tail
    int s0 = csr_src[p];
    const float4* q = (const float4*)ea_csr + p * 4;
    float4 e00 = q[0], e01 = q[1], e02 = q[2], e03 = q[3];
    int b0 = s0 * HC;
    float xs0[NH];
    #pragma unroll
    for (int h = 0; h < NH; h++) xs0[h] = xlL[b0 + h * CD];
    float sc0[NH];
    SCORE1(e00, e01, e02, e03, xs0, sc0);
    #pragma unroll
    for (int off = 1; off < 64; off <<= 1) {
      #pragma unroll
      for (int h = 0; h < NH; h++) sc0[h] += __shfl_xor(sc0[h], off, 64);
    }
    #pragma unroll
    for (int h = 0; h < NH; h++) {
      float mn = fmaxf(m[h], sc0[h]);
      float r  = __expf(m[h] - mn);
      float g0 = __expf(sc0[h] - mn);
      l[h]   = l[h] * r + g0;
      acc[h] = acc[h] * r + g0 * xs0[h];
      m[h] = mn;
    }
  }

  float v = 0.f;
  #pragma unroll
  for (int h = 0; h < NH; h++) v += acc[h] / l[h];
  v = v * (1.0f / NH) + bias[lane];
  v = v > 0.f ? v : expm1f(v);
  out[d * CD + lane] = v;
}

extern "C" void kernel_launch(void* const* d_in, const int* in_sizes, int n_in,
                              void* d_out, int out_size, void* d_ws, size_t ws_size,
                              hipStream_t stream) {
  const float* x = (const float*)d_in[0];
  const int* ei = (const int*)d_in[1];      // [2, NE]: src row then dst row
  const float* eattr = (const float*)d_in[2];

  char* w = (char*)d_ws;
  int* degi      = (int*)w;                 w += NN * 4;
  int* cursor    = (int*)w;                 w += NN * 4;
  int* rowptr    = (int*)w;                 w += (NN + 1) * 4;
  int* csr_eid   = (int*)w;                 w += NE * 4;
  int* csr_src   = (int*)w;                 w += NE * 4;
  float* loop_attr = (float*)w;             w += (size_t)NN * ED * 4;
  float* ea_csr  = (float*)w;               w += (size_t)NE * ED * 4;
  float* xl      = (float*)w;               w += (size_t)NN * HC * 4;
  float* hbuf    = (float*)w;               w += (size_t)NN * CD * 4;

  // graph structure + permuted edge attrs (layer-invariant)
  hipMemsetAsync(degi, 0, NN * 4, stream);
  hipMemsetAsync(cursor, 0, NN * 4, stream);
  k_count<<<(NE + 255) / 256, 256, 0, stream>>>(ei + NE, degi);
  k_scan<<<1, 256, 0, stream>>>(degi, rowptr);
  k_fill<<<(NE + 255) / 256, 256, 0, stream>>>(ei, rowptr, cursor, csr_eid, csr_src);
  k_loopattr<<<(NN + 3) / 4, 256, 0, stream>>>(csr_eid, rowptr, eattr, loop_attr);
  k_eacsr<<<(NE * 4 + 255) / 256, 256, 0, stream>>>(csr_eid, eattr, ea_csr);

  for (int l = 0; l < 3; l++) {
    const float* Wl  = (const float*)d_in[3 + 5 * l];
    const float* bl  = (const float*)d_in[4 + 5 * l];
    const float* We  = (const float*)d_in[5 + 5 * l];
    const float* att = (const float*)d_in[6 + 5 * l];
    const float* b   = (const float*)d_in[7 + 5 * l];

    if (l == 0) k_xl<ND><<<NN / 8, 320, 0, stream>>>(x, Wl, bl, xl);
    else        k_xl<CD><<<NN / 8, 320, 0, stream>>>(hbuf, Wl, bl, xl);

    float* dst_out = (l < 2) ? hbuf : (float*)d_out;
    k_fused<<<(NN + 3) / 4, 256, 0, stream>>>(csr_src, rowptr, ea_csr, loop_attr,
                                              xl, We, att, b, dst_out);
  }
}